// Round 1
// baseline (2589.460 us; speedup 1.0000x reference)
//
#include <hip/hip_runtime.h>
#include <math.h>

#define NB   8192
#define NE   8
#define NF1  1024
#define NF2  2048
#define NC   100
#define NTILES 256
#define RMAX 36          // max rows per tile (guaranteed by scan)
#define KT   16          // k-tile for phase A
#define CHUNK 512        // F2 chunk
#define SUBK 64          // phase-B K sub-tile
#define LC   (NC + 4)    // padded logits/W2t cols = 104

// ws int layout
#define WS_COUNTS 0      // 8
#define WS_OFF    8      // 9
#define WS_CUR    17     // 9
#define WS_TP     32     // 9 (tile prefix)
#define WS_TE     48     // 8 (tiles per expert)
#define WS_ROWS   64     // NB row indices

struct Smem {
    float Xt[KT][RMAX];          // k-major x tile (broadcast reads)
    float W1t[KT][CHUNK];        // contiguous b128 reads
    float Hc[RMAX][CHUNK + 1];   // stride 513 -> conflict-free column reads
    float W2t[SUBK][LC];
    float logits[RMAX][LC];
    int   rows[RMAX];
    int   hdr[3];                // e, rbase, nrows
};

__global__ void k_zero(int* ws) {
    if (threadIdx.x < 64) ws[threadIdx.x] = 0;
}

__global__ void k_hist(const int* __restrict__ dom, int* ws) {
    int b = blockIdx.x * 256 + threadIdx.x;
    if (b < NB) atomicAdd(&ws[WS_COUNTS + dom[b]], 1);
}

// single-thread: offsets, cursors, and a proportional tile allocation with
// Sum(te) == NTILES and rows-per-tile <= RMAX.
__global__ void k_scan(int* ws) {
    if (threadIdx.x != 0 || blockIdx.x != 0) return;
    ws[WS_OFF + 0] = 0;
    int tot = 0;
    for (int e = 0; e < NE; ++e) {
        int c = ws[WS_COUNTS + e];
        ws[WS_OFF + e + 1] = ws[WS_OFF + e] + c;
        ws[WS_CUR + e] = ws[WS_OFF + e];
        int t = (c + RMAX - 1) / RMAX;
        ws[WS_TE + e] = t;
        tot += t;
    }
    int spare = NTILES - tot;
    while (spare > 0) {
        int best = 0, bm = -1;
        for (int e = 0; e < NE; ++e) {
            int t = ws[WS_TE + e];
            int c = ws[WS_COUNTS + e];
            int m = (t > 0) ? (c + t - 1) / t : c;  // current rows/tile
            if (m > bm) { bm = m; best = e; }
        }
        ws[WS_TE + best] += 1;
        --spare;
    }
    ws[WS_TP + 0] = 0;
    for (int e = 0; e < NE; ++e) ws[WS_TP + e + 1] = ws[WS_TP + e] + ws[WS_TE + e];
}

__global__ void k_scatter(const int* __restrict__ dom, int* ws) {
    int b = blockIdx.x * 256 + threadIdx.x;
    if (b < NB) {
        int e = dom[b];
        int p = atomicAdd(&ws[WS_CUR + e], 1);
        ws[WS_ROWS + p] = b;
    }
}

// RPG = rows per row-group (4 groups). NR = RPG*4 padded rows (32 or 36).
template <int RPG>
__device__ __forceinline__ void run_tile(
    Smem& sm, const int tid, const int e, const int nrows,
    const float* __restrict__ x, const float* __restrict__ W1,
    const float* __restrict__ b1, const float* __restrict__ W2,
    const float* __restrict__ b2, float* __restrict__ out)
{
    constexpr int NR = RPG * 4;
    constexpr int BR = (RPG == 8) ? 4 : 5;   // phase-B rows per thread

    // phase A mapping: 4 row-groups x 64 col-groups
    const int rg = tid >> 6;
    const int cg = tid & 63;
    // phase B mapping: wave k-slice x 8 row-groups x 8 lanes
    const int ks  = tid >> 6;
    const int brg = (tid >> 3) & 7;
    const int bl  = tid & 7;

    int rrB[BR];
#pragma unroll
    for (int i = 0; i < BR; ++i) {
        int r = brg * BR + i;
        rrB[i] = (r < NR) ? r : (NR - 1);   // clamp padded rows (dup, guarded later)
    }

    float accB[BR][13];
#pragma unroll
    for (int i = 0; i < BR; ++i)
#pragma unroll
        for (int j = 0; j < 13; ++j) accB[i][j] = 0.f;

    for (int chunk = 0; chunk < NF2 / CHUNK; ++chunk) {
        const size_t w1base = ((size_t)e * NF1) * NF2 + (size_t)chunk * CHUNK;

        // per-thread output-column biases for this chunk
        float bias[8];
#pragma unroll
        for (int q = 0; q < 8; ++q) {
            const int c = (q < 4) ? (cg * 4 + q) : (256 + cg * 4 + (q - 4));
            bias[q] = b1[e * NF2 + chunk * CHUNK + c];
        }

        float accA[RPG][8];
#pragma unroll
        for (int i = 0; i < RPG; ++i)
#pragma unroll
            for (int q = 0; q < 8; ++q) accA[i][q] = 0.f;

        // register double-buffered staging
        float2 xp[2];
        float4 wp[8];
        const int wkk = tid >> 4;   // 0..15
        const int wfi = tid & 15;   // 0..15

        auto load_tile = [&](int kt) {
            const int k0 = kt * KT;
#pragma unroll
            for (int u = 0; u < 2; ++u) {
                const int idx = tid + 256 * u;
                if (idx < (KT / 2) * RMAX) {               // 288 float2 pairs
                    const int r   = idx % RMAX;
                    const int kk2 = idx / RMAX;            // 0..7
                    xp[u] = *(const float2*)&x[(size_t)sm.rows[r] * NF1 + k0 + kk2 * 2];
                }
            }
#pragma unroll
            for (int u = 0; u < 8; ++u)
                wp[u] = *(const float4*)&W1[w1base + (size_t)(k0 + wkk) * NF2 + (wfi + 16 * u) * 4];
        };
        auto store_tile = [&]() {
#pragma unroll
            for (int u = 0; u < 2; ++u) {
                const int idx = tid + 256 * u;
                if (idx < (KT / 2) * RMAX) {
                    const int r   = idx % RMAX;
                    const int kk2 = idx / RMAX;
                    sm.Xt[kk2 * 2][r]     = xp[u].x;
                    sm.Xt[kk2 * 2 + 1][r] = xp[u].y;
                }
            }
#pragma unroll
            for (int u = 0; u < 8; ++u)
                *(float4*)&sm.W1t[wkk][(wfi + 16 * u) * 4] = wp[u];
        };

        load_tile(0);
        for (int kt = 0; kt < NF1 / KT; ++kt) {
            __syncthreads();           // previous tile fully consumed
            store_tile();
            __syncthreads();
            if (kt + 1 < NF1 / KT) load_tile(kt + 1);  // overlap with compute
#pragma unroll
            for (int kk = 0; kk < KT; ++kk) {
                const float4 bv0 = *(const float4*)&sm.W1t[kk][cg * 4];
                const float4 bv1 = *(const float4*)&sm.W1t[kk][cg * 4 + 256];
#pragma unroll
                for (int i = 0; i < RPG; ++i) {
                    const float a = sm.Xt[kk][rg * RPG + i];
                    accA[i][0] = fmaf(a, bv0.x, accA[i][0]);
                    accA[i][1] = fmaf(a, bv0.y, accA[i][1]);
                    accA[i][2] = fmaf(a, bv0.z, accA[i][2]);
                    accA[i][3] = fmaf(a, bv0.w, accA[i][3]);
                    accA[i][4] = fmaf(a, bv1.x, accA[i][4]);
                    accA[i][5] = fmaf(a, bv1.y, accA[i][5]);
                    accA[i][6] = fmaf(a, bv1.z, accA[i][6]);
                    accA[i][7] = fmaf(a, bv1.w, accA[i][7]);
                }
            }
        }

        // Hc = relu(acc + bias)
#pragma unroll
        for (int i = 0; i < RPG; ++i) {
            const int r = rg * RPG + i;
#pragma unroll
            for (int q = 0; q < 8; ++q) {
                const int c = (q < 4) ? (cg * 4 + q) : (256 + cg * 4 + (q - 4));
                sm.Hc[r][c] = fmaxf(accA[i][q] + bias[q], 0.f);
            }
        }
        __syncthreads();

        // phase B: logits += Hc @ W2[chunk rows]
        for (int sub = 0; sub < CHUNK / SUBK; ++sub) {
            for (int idx = tid; idx < SUBK * LC; idx += 256) {
                const int f = idx / LC;
                const int c = idx - f * LC;
                float v = 0.f;
                if (c < NC)
                    v = W2[((size_t)e * NF2 + chunk * CHUNK + sub * SUBK + f) * NC + c];
                sm.W2t[f][c] = v;
            }
            __syncthreads();
#pragma unroll
            for (int ff = 0; ff < 16; ++ff) {
                const int fl = ks * 16 + ff;
                float h[BR];
#pragma unroll
                for (int i = 0; i < BR; ++i) h[i] = sm.Hc[rrB[i]][sub * SUBK + fl];
#pragma unroll
                for (int j = 0; j < 13; ++j) {
                    const float w = sm.W2t[fl][bl + 8 * j];
#pragma unroll
                    for (int i = 0; i < BR; ++i) accB[i][j] = fmaf(h[i], w, accB[i][j]);
                }
            }
            __syncthreads();
        }
    }

    // merge 4-way wave partials into logits
#pragma unroll
    for (int i = 0; i < BR; ++i) {
        const int r = brg * BR + i;
        if (r < NR) {
#pragma unroll
            for (int j = 0; j < 13; ++j)
                atomicAdd(&sm.logits[r][bl + 8 * j], accB[i][j]);
        }
    }
    __syncthreads();

    // softmax: 8 lanes per row
    for (int r0 = tid >> 3; r0 < nrows; r0 += 32) {
        const int l = tid & 7;
        float v[13];
        float m = -1e30f;
#pragma unroll
        for (int j = 0; j < 13; ++j) {
            const int c = l + 8 * j;
            v[j] = (c < NC) ? (sm.logits[r0][c] + b2[e * NC + c]) : -1e30f;
            m = fmaxf(m, v[j]);
        }
#pragma unroll
        for (int s = 1; s < 8; s <<= 1) m = fmaxf(m, __shfl_xor(m, s));
        float p[13];
        float ssum = 0.f;
#pragma unroll
        for (int j = 0; j < 13; ++j) {
            const int c = l + 8 * j;
            p[j] = (c < NC) ? __expf(v[j] - m) : 0.f;
            ssum += p[j];
        }
#pragma unroll
        for (int s = 1; s < 8; s <<= 1) ssum += __shfl_xor(ssum, s);
        const float inv = 1.f / ssum;
        const size_t ob = (size_t)sm.rows[r0] * NC;
#pragma unroll
        for (int j = 0; j < 13; ++j) {
            const int c = l + 8 * j;
            if (c < NC) out[ob + c] = p[j] * inv;
        }
    }
}

__global__ __launch_bounds__(256, 1) void k_moe(
    const int* __restrict__ ws, const float* __restrict__ x,
    const float* __restrict__ W1, const float* __restrict__ b1,
    const float* __restrict__ W2, const float* __restrict__ b2,
    float* __restrict__ out)
{
    __shared__ Smem sm;
    const int tid = threadIdx.x;
    if (tid == 0) {
        const int tile = blockIdx.x;
        const int* tp = ws + WS_TP;
        int e = 0;
        while (!(tile >= tp[e] && tile < tp[e + 1])) {
            ++e;
            if (e >= NE) { e = NE - 1; break; }
        }
        const int j   = tile - tp[e];
        const int cnt = ws[WS_COUNTS + e];
        const int te  = ws[WS_TE + e];
        int nr = 0, row0 = 0;
        if (te > 0) {
            const int base = cnt / te;
            const int rem  = cnt % te;
            row0 = j * base + ((j < rem) ? j : rem);
            nr   = base + ((j < rem) ? 1 : 0);
        }
        sm.hdr[0] = e;
        sm.hdr[1] = ws[WS_OFF + e] + row0;
        sm.hdr[2] = nr;
    }
    __syncthreads();
    const int e = sm.hdr[0];
    const int rbase = sm.hdr[1];
    const int nrows = sm.hdr[2];
    if (nrows <= 0) return;
    if (tid < RMAX)
        sm.rows[tid] = ws[WS_ROWS + rbase + ((tid < nrows) ? tid : (nrows - 1))];
    for (int i = tid; i < RMAX * LC; i += 256) (&sm.logits[0][0])[i] = 0.f;
    __syncthreads();

    if (nrows <= 32) run_tile<8>(sm, tid, e, nrows, x, W1, b1, W2, b2, out);
    else             run_tile<9>(sm, tid, e, nrows, x, W1, b1, W2, b2, out);
}

extern "C" void kernel_launch(void* const* d_in, const int* in_sizes, int n_in,
                              void* d_out, int out_size, void* d_ws, size_t ws_size,
                              hipStream_t stream)
{
    const int*   dom = (const int*)d_in[0];
    const float* x   = (const float*)d_in[1];
    const float* W1  = (const float*)d_in[2];
    const float* b1  = (const float*)d_in[3];
    const float* W2  = (const float*)d_in[4];
    const float* b2  = (const float*)d_in[5];
    float*       out = (float*)d_out;
    int*         ws  = (int*)d_ws;

    hipLaunchKernelGGL(k_zero,    dim3(1),        dim3(64),  0, stream, ws);
    hipLaunchKernelGGL(k_hist,    dim3(NB / 256), dim3(256), 0, stream, dom, ws);
    hipLaunchKernelGGL(k_scan,    dim3(1),        dim3(1),   0, stream, ws);
    hipLaunchKernelGGL(k_scatter, dim3(NB / 256), dim3(256), 0, stream, dom, ws);
    hipLaunchKernelGGL(k_moe,     dim3(NTILES),   dim3(256), 0, stream,
                       ws, x, W1, b1, W2, b2, out);
}

// Round 2
// 513.285 us; speedup vs baseline: 5.0449x; 5.0449x over previous
//
#include <hip/hip_runtime.h>
#include <math.h>

#define NB 8192
#define NE 8
#define F1 1024
#define F2 2048
#define NC 100
#define TM 128           // rows per tile
#define CCW 128          // F2 cols per block
#define NCC (F2 / CCW)   // 16
#define MAXTY 72         // >= sum_e ceil(c_e/128) always (64 + 8)

#define WS_COUNTS 0
#define WS_OFF 8
#define WS_CUR 17
#define WS_ROWS 64

typedef float f32x4 __attribute__((ext_vector_type(4)));
typedef short s16x8 __attribute__((ext_vector_type(8)));
typedef unsigned short u16x4 __attribute__((ext_vector_type(4)));

__device__ __forceinline__ unsigned short bf_hi(float f) {
    unsigned u = __float_as_uint(f);
    return (unsigned short)((u + 0x7FFFu + ((u >> 16) & 1u)) >> 16);  // RNE
}
__device__ __forceinline__ float bf_up(unsigned short h) {
    return __uint_as_float(((unsigned)h) << 16);
}
// slot swizzle: spreads scatter-writes across banks; reads stay contiguous
__device__ __forceinline__ int swz(int g, int sl) {
    return sl ^ ((g ^ (g >> 3)) & 7);
}

__global__ void k_hist(const int* __restrict__ dom, int* ws) {
    int b = blockIdx.x * 256 + threadIdx.x;
    if (b < NB) atomicAdd(&ws[WS_COUNTS + dom[b]], 1);
}

__global__ void k_scan(int* ws) {
    if (threadIdx.x != 0 || blockIdx.x != 0) return;
    ws[WS_OFF + 0] = 0;
    for (int e = 0; e < NE; ++e) {
        ws[WS_OFF + e + 1] = ws[WS_OFF + e] + ws[WS_COUNTS + e];
        ws[WS_CUR + e] = ws[WS_OFF + e];
    }
}

__global__ void k_scatter(const int* __restrict__ dom, int* ws) {
    int b = blockIdx.x * 256 + threadIdx.x;
    if (b < NB) {
        int p = atomicAdd(&ws[WS_CUR + dom[b]], 1);
        ws[WS_ROWS + p] = b;
    }
}

__global__ __launch_bounds__(256, 2) void k_g1(
    const int* __restrict__ ws, const float* __restrict__ x,
    const float* __restrict__ W1, const float* __restrict__ b1,
    const float* __restrict__ W2, float* __restrict__ out)
{
    __shared__ union {
        struct { unsigned short Ah[4096], Al[4096], Bh[4096], Bl[4096]; } pa;
        struct { unsigned short Hh[8192], Hl[8192], Wh[8192], Wl[8192]; } pb;
    } sm;
    __shared__ int rows[TM];
    __shared__ int hdr[3];

    const int tid = threadIdx.x;
    const int cc = blockIdx.x;

    if (tid == 0) {
        int ty = blockIdx.y, acc = 0, e = -1, t = 0;
        for (int i = 0; i < NE; ++i) {
            int te = (ws[WS_COUNTS + i] + TM - 1) / TM;
            if (ty < acc + te) { e = i; t = ty - acc; break; }
            acc += te;
        }
        hdr[0] = e;
        if (e >= 0) {
            int cnt = ws[WS_COUNTS + e];
            hdr[1] = min(TM, cnt - t * TM);
            hdr[2] = ws[WS_OFF + e] + t * TM;
        }
    }
    __syncthreads();
    const int e = hdr[0];
    if (e < 0) return;
    const int nr = hdr[1];
    const int rbase = hdr[2];
    if (tid < TM) rows[tid] = ws[WS_ROWS + rbase + min(tid, nr - 1)];

    const int wave = tid >> 6, lane = tid & 63;
    const int wm = wave >> 1, wn = wave & 1;
    const int lg = lane >> 4, ln = lane & 15;

    f32x4 acc[4][4];
#pragma unroll
    for (int m = 0; m < 4; ++m)
#pragma unroll
        for (int n = 0; n < 4; ++n) acc[m][n] = (f32x4){0.f, 0.f, 0.f, 0.f};

    float bias[4];
#pragma unroll
    for (int nf = 0; nf < 4; ++nf)
        bias[nf] = b1[e * F2 + cc * CCW + wn * 64 + nf * 16 + ln];

    __syncthreads();  // rows[] visible before first gather

    for (int kt = 0; kt < F1 / 32; ++kt) {
        const int k0 = kt * 32;
        float4 av[2][2];
#pragma unroll
        for (int i = 0; i < 2; ++i) {
            int unit = tid + 256 * i;
            int r = unit >> 2, kc = unit & 3;
            const float* p = x + (size_t)rows[r] * F1 + k0 + kc * 8;
            av[i][0] = *(const float4*)p;
            av[i][1] = *(const float4*)(p + 4);
        }
        float4 bv[4];
#pragma unroll
        for (int i = 0; i < 4; ++i) {
            int unit = tid + 256 * i;
            int k = unit >> 5, nq = unit & 31;
            bv[i] = *(const float4*)(W1 + ((size_t)e * F1 + k0 + k) * F2 + cc * CCW + nq * 4);
        }
        __syncthreads();  // previous tile's frag reads complete
#pragma unroll
        for (int i = 0; i < 2; ++i) {
            int unit = tid + 256 * i;
            int r = unit >> 2, kc = unit & 3;
            int mf = r >> 4, m = r & 15, jb = kc >> 1;
            float f[8] = {av[i][0].x, av[i][0].y, av[i][0].z, av[i][0].w,
                          av[i][1].x, av[i][1].y, av[i][1].z, av[i][1].w};
#pragma unroll
            for (int half = 0; half < 2; ++half) {
                int g = mf * 4 + (kc & 1) * 2 + half;
                int base = (g * 16 + swz(g, m)) * 8 + jb * 4;
                u16x4 hv, lv;
#pragma unroll
                for (int t = 0; t < 4; ++t) {
                    float v = f[half * 4 + t];
                    unsigned short h = bf_hi(v);
                    hv[t] = h;
                    lv[t] = bf_hi(v - bf_up(h));
                }
                *(u16x4*)&sm.pa.Ah[base] = hv;
                *(u16x4*)&sm.pa.Al[base] = lv;
            }
        }
#pragma unroll
        for (int i = 0; i < 4; ++i) {
            int unit = tid + 256 * i;
            int k = unit >> 5, nq = unit & 31;
            int kg = (k & 15) >> 2, j = (k & 3) | ((k >> 4) << 2);
            int g = (nq >> 2) * 4 + kg, nb = (nq & 3) * 4;
            float f[4] = {bv[i].x, bv[i].y, bv[i].z, bv[i].w};
#pragma unroll
            for (int t = 0; t < 4; ++t) {
                int idx = (g * 16 + swz(g, nb + t)) * 8 + j;
                unsigned short h = bf_hi(f[t]);
                sm.pa.Bh[idx] = h;
                sm.pa.Bl[idx] = bf_hi(f[t] - bf_up(h));
            }
        }
        __syncthreads();
        s16x8 ah[4], al[4];
#pragma unroll
        for (int m = 0; m < 4; ++m) {
            int g = (wm * 4 + m) * 4 + lg;
            int idx = (g * 16 + swz(g, ln)) * 8;
            ah[m] = *(const s16x8*)&sm.pa.Ah[idx];
            al[m] = *(const s16x8*)&sm.pa.Al[idx];
        }
#pragma unroll
        for (int n = 0; n < 4; ++n) {
            int g = (wn * 4 + n) * 4 + lg;
            int idx = (g * 16 + swz(g, ln)) * 8;
            s16x8 bh = *(const s16x8*)&sm.pa.Bh[idx];
            s16x8 bl = *(const s16x8*)&sm.pa.Bl[idx];
#pragma unroll
            for (int m = 0; m < 4; ++m) {
                acc[m][n] = __builtin_amdgcn_mfma_f32_16x16x32_bf16(ah[m], bh, acc[m][n], 0, 0, 0);
                acc[m][n] = __builtin_amdgcn_mfma_f32_16x16x32_bf16(al[m], bh, acc[m][n], 0, 0, 0);
                acc[m][n] = __builtin_amdgcn_mfma_f32_16x16x32_bf16(ah[m], bl, acc[m][n], 0, 0, 0);
            }
        }
    }

    // ---- phase B: logits partial = relu(h+b1) @ W2[cc-slice], fused ----
    f32x4 accB[2][8];
#pragma unroll
    for (int ci = 0; ci < 2; ++ci)
#pragma unroll
        for (int mf = 0; mf < 8; ++mf) accB[ci][mf] = (f32x4){0.f, 0.f, 0.f, 0.f};

#pragma unroll
    for (int s = 0; s < 2; ++s) {
        __syncthreads();  // prior sub's (or phase A's) LDS reads complete
        if (wn == s) {
#pragma unroll
            for (int m = 0; m < 4; ++m)
#pragma unroll
                for (int nf = 0; nf < 4; ++nf) {
                    int kk = nf * 16 + ln;
                    int kb = kk >> 5, kg = (kk & 15) >> 2;
                    int j = (kk & 3) | (((kk >> 4) & 1) << 2);
                    int g = (wm * 4 + m) * 8 + kb * 4 + kg;
                    float b = bias[nf];
#pragma unroll
                    for (int reg = 0; reg < 4; ++reg) {
                        float v = fmaxf(acc[m][nf][reg] + b, 0.f);
                        unsigned short h = bf_hi(v);
                        int idx = (g * 16 + swz(g, lg * 4 + reg)) * 8 + j;
                        sm.pb.Hh[idx] = h;
                        sm.pb.Hl[idx] = bf_hi(v - bf_up(h));
                    }
                }
        }
#pragma unroll
        for (int i = 0; i < 8; ++i) {
            int unit = tid + 256 * i;
            int k = unit >> 5, cq = unit & 31, c0 = cq * 4;
            float4 wv = {0.f, 0.f, 0.f, 0.f};
            if (c0 < NC)
                wv = *(const float4*)(W2 + ((size_t)e * F2 + cc * CCW + s * 64 + k) * NC + c0);
            int kb = k >> 5, kg = (k & 15) >> 2;
            int j = (k & 3) | (((k >> 4) & 1) << 2);
            int g = (cq >> 2) * 8 + kb * 4 + kg;
            float f[4] = {wv.x, wv.y, wv.z, wv.w};
#pragma unroll
            for (int t = 0; t < 4; ++t) {
                int idx = (g * 16 + swz(g, (c0 & 15) + t)) * 8 + j;
                unsigned short h = bf_hi(f[t]);
                sm.pb.Wh[idx] = h;
                sm.pb.Wl[idx] = bf_hi(f[t] - bf_up(h));
            }
        }
        __syncthreads();
#pragma unroll
        for (int ci = 0; ci < 2; ++ci) {
            int cf = wave + ci * 4;
#pragma unroll
            for (int kb = 0; kb < 2; ++kb) {
                int gw = cf * 8 + kb * 4 + lg;
                int wi = (gw * 16 + swz(gw, ln)) * 8;
                s16x8 wh = *(const s16x8*)&sm.pb.Wh[wi];
                s16x8 wl = *(const s16x8*)&sm.pb.Wl[wi];
#pragma unroll
                for (int mf = 0; mf < 8; ++mf) {
                    int gh = mf * 8 + kb * 4 + lg;
                    int hb = (gh * 16 + swz(gh, ln)) * 8;
                    s16x8 hh = *(const s16x8*)&sm.pb.Hh[hb];
                    s16x8 hl = *(const s16x8*)&sm.pb.Hl[hb];
                    accB[ci][mf] = __builtin_amdgcn_mfma_f32_16x16x32_bf16(hh, wh, accB[ci][mf], 0, 0, 0);
                    accB[ci][mf] = __builtin_amdgcn_mfma_f32_16x16x32_bf16(hl, wh, accB[ci][mf], 0, 0, 0);
                    accB[ci][mf] = __builtin_amdgcn_mfma_f32_16x16x32_bf16(hh, wl, accB[ci][mf], 0, 0, 0);
                }
            }
        }
    }

#pragma unroll
    for (int ci = 0; ci < 2; ++ci) {
        int c = (wave + ci * 4) * 16 + ln;
        if (c < NC) {
#pragma unroll
            for (int mf = 0; mf < 8; ++mf)
#pragma unroll
                for (int reg = 0; reg < 4; ++reg) {
                    int ml = mf * 16 + lg * 4 + reg;
                    if (ml < nr)
                        atomicAdd(out + (size_t)rows[ml] * NC + c, accB[ci][mf][reg]);
                }
        }
    }
}

__global__ void k_sm(const int* __restrict__ dom, const float* __restrict__ b2,
                     float* __restrict__ out)
{
    const int row = blockIdx.x * 4 + (threadIdx.x >> 6);
    const int lane = threadIdx.x & 63;
    const int e = dom[row];
    float* base = out + (size_t)row * NC;
    float v0 = base[lane] + b2[e * NC + lane];
    float v1 = -1e30f;
    if (lane + 64 < NC) v1 = base[lane + 64] + b2[e * NC + lane + 64];
    float m = fmaxf(v0, v1);
#pragma unroll
    for (int s = 1; s < 64; s <<= 1) m = fmaxf(m, __shfl_xor(m, s));
    float p0 = expf(v0 - m);
    float p1 = (lane + 64 < NC) ? expf(v1 - m) : 0.f;
    float sum = p0 + p1;
#pragma unroll
    for (int s = 1; s < 64; s <<= 1) sum += __shfl_xor(sum, s);
    float inv = 1.f / sum;
    base[lane] = p0 * inv;
    if (lane + 64 < NC) base[lane + 64] = p1 * inv;
}

extern "C" void kernel_launch(void* const* d_in, const int* in_sizes, int n_in,
                              void* d_out, int out_size, void* d_ws, size_t ws_size,
                              hipStream_t stream)
{
    const int*   dom = (const int*)d_in[0];
    const float* x   = (const float*)d_in[1];
    const float* W1  = (const float*)d_in[2];
    const float* b1  = (const float*)d_in[3];
    const float* W2  = (const float*)d_in[4];
    const float* b2  = (const float*)d_in[5];
    float*       out = (float*)d_out;
    int*         ws  = (int*)d_ws;

    hipMemsetAsync(ws, 0, 64 * sizeof(int), stream);
    hipMemsetAsync(out, 0, (size_t)NB * NC * sizeof(float), stream);
    hipLaunchKernelGGL(k_hist,    dim3(NB / 256), dim3(256), 0, stream, dom, ws);
    hipLaunchKernelGGL(k_scan,    dim3(1),        dim3(1),   0, stream, ws);
    hipLaunchKernelGGL(k_scatter, dim3(NB / 256), dim3(256), 0, stream, dom, ws);
    hipLaunchKernelGGL(k_g1,      dim3(NCC, MAXTY), dim3(256), 0, stream,
                       ws, x, W1, b1, W2, out);
    hipLaunchKernelGGL(k_sm,      dim3(NB / 4),   dim3(256), 0, stream, dom, b2, out);
}

// Round 3
// 426.261 us; speedup vs baseline: 6.0748x; 1.2042x over previous
//
#include <hip/hip_runtime.h>
#include <math.h>

#define NB 8192
#define NE 8
#define F1 1024
#define F2 2048
#define NC 100
#define NCP 112
#define TM 128
#define BK 64
#define NCC (F2 / 128)   // 16
#define MAXTY 72

#define WS_COUNTS 0
#define WS_OFF 8
#define WS_CUR 17
#define WS_ROWS 64

#define OFF_XH  ((size_t)65536)
#define SZ_X    ((size_t)NB * F1)          // elements per x plane
#define OFF_W1H (OFF_XH + 4 * SZ_X)
#define SZ_W1   ((size_t)NE * F2 * F1)     // elements per W1t plane
#define OFF_W2H (OFF_W1H + 4 * SZ_W1)
#define SZ_W2   ((size_t)NE * NCP * F2)    // elements per W2t plane

typedef float f32x4 __attribute__((ext_vector_type(4)));
typedef short s16x8 __attribute__((ext_vector_type(8)));
typedef unsigned short u16x8 __attribute__((ext_vector_type(8)));
typedef unsigned short u16x4 __attribute__((ext_vector_type(4)));

__device__ __forceinline__ unsigned short bf_hi(float f) {
    unsigned u = __float_as_uint(f);
    return (unsigned short)((u + 0x7FFFu + ((u >> 16) & 1u)) >> 16);  // RNE
}
__device__ __forceinline__ float bf_up(unsigned short h) {
    return __uint_as_float(((unsigned)h) << 16);
}

typedef const __attribute__((address_space(1))) unsigned cgu;
typedef __attribute__((address_space(3))) unsigned ldu;
__device__ __forceinline__ void gl16(const void* g, void* l) {
    __builtin_amdgcn_global_load_lds((cgu*)g, (ldu*)l, 16, 0, 0);
}

__global__ void k_hist(const int* __restrict__ dom, int* ws) {
    int b = blockIdx.x * 256 + threadIdx.x;
    if (b < NB) atomicAdd(&ws[WS_COUNTS + dom[b]], 1);
}

__global__ void k_scan(int* ws) {
    if (threadIdx.x != 0 || blockIdx.x != 0) return;
    ws[WS_OFF + 0] = 0;
    for (int e = 0; e < NE; ++e) {
        ws[WS_OFF + e + 1] = ws[WS_OFF + e] + ws[WS_COUNTS + e];
        ws[WS_CUR + e] = ws[WS_OFF + e];
    }
}

__global__ void k_scatter(const int* __restrict__ dom, int* ws) {
    int b = blockIdx.x * 256 + threadIdx.x;
    if (b < NB) {
        int p = atomicAdd(&ws[WS_CUR + dom[b]], 1);
        ws[WS_ROWS + p] = b;
    }
}

// x[f32 8192x1024] -> xh, xl bf16 planes (row-major, same layout)
__global__ void k_split_x(const float* __restrict__ x, unsigned short* __restrict__ xh) {
    unsigned short* xl = xh + SZ_X;
    size_t i = (size_t)blockIdx.x * 256 + threadIdx.x;   // one float4 per thread
    float4 v = *(const float4*)(x + i * 4);
    u16x4 h, l;
    float f[4] = {v.x, v.y, v.z, v.w};
#pragma unroll
    for (int t = 0; t < 4; ++t) {
        unsigned short hh = bf_hi(f[t]);
        h[t] = hh;
        l[t] = bf_hi(f[t] - bf_up(hh));
    }
    *(u16x4*)(xh + i * 4) = h;
    *(u16x4*)(xl + i * 4) = l;
}

// W1[e][k][n] f32 -> W1t[e][n][k] bf16 hi/lo planes (64x64 LDS tile transpose)
__global__ void k_split_w1t(const float* __restrict__ W1, unsigned short* __restrict__ w1h) {
    unsigned short* w1l = w1h + SZ_W1;
    __shared__ float t[64][68];
    const int e = blockIdx.z, k0 = blockIdx.y * 64, n0 = blockIdx.x * 64;
    const float* src = W1 + ((size_t)e * F1 + k0) * F2 + n0;
#pragma unroll
    for (int i = 0; i < 4; ++i) {
        int u = threadIdx.x + 256 * i;
        int k = u >> 4, n4 = (u & 15) * 4;
        float4 v = *(const float4*)(src + (size_t)k * F2 + n4);
        t[k][n4] = v.x; t[k][n4 + 1] = v.y; t[k][n4 + 2] = v.z; t[k][n4 + 3] = v.w;
    }
    __syncthreads();
#pragma unroll
    for (int i = 0; i < 2; ++i) {
        int u = threadIdx.x + 256 * i;
        int n = u >> 3, kg = u & 7;
        u16x8 hv, lv;
#pragma unroll
        for (int j = 0; j < 8; ++j) {
            float v = t[kg * 8 + j][n];
            unsigned short hh = bf_hi(v);
            hv[j] = hh;
            lv[j] = bf_hi(v - bf_up(hh));
        }
        size_t dst = ((size_t)e * F2 + n0 + n) * F1 + k0 + kg * 8;
        *(u16x8*)(w1h + dst) = hv;
        *(u16x8*)(w1l + dst) = lv;
    }
}

// W2[e][k2][c] f32 -> W2t[e][c(pad112)][k2] bf16 hi/lo planes
__global__ void k_split_w2t(const float* __restrict__ W2, unsigned short* __restrict__ w2h) {
    unsigned short* w2l = w2h + SZ_W2;
    __shared__ float t[64][NC + 4];
    const int e = blockIdx.y, k0 = blockIdx.x * 64;
    const float* src = W2 + ((size_t)e * F2 + k0) * NC;
    for (int u = threadIdx.x; u < 64 * NC; u += 256) {
        int k = u / NC, c = u - k * NC;
        t[k][c] = src[u];
    }
    __syncthreads();
#pragma unroll
    for (int i = 0; i < 4; ++i) {
        int u = threadIdx.x + 256 * i;
        if (u < NCP * 8) {
            int c = u >> 3, kg = u & 7;
            u16x8 hv, lv;
#pragma unroll
            for (int j = 0; j < 8; ++j) {
                float v = (c < NC) ? t[kg * 8 + j][c] : 0.f;
                unsigned short hh = bf_hi(v);
                hv[j] = hh;
                lv[j] = bf_hi(v - bf_up(hh));
            }
            size_t dst = ((size_t)e * NCP + c) * F2 + k0 + kg * 8;
            *(u16x8*)(w2h + dst) = hv;
            *(u16x8*)(w2l + dst) = lv;
        }
    }
}

// Fragment-packed LDS layout: element (row, kg, j) at ushort (row*64 + (kg ^ (row&7))*8 + j)
__global__ __launch_bounds__(256, 2) void k_g1(
    const int* __restrict__ ws, const unsigned short* __restrict__ xh,
    const unsigned short* __restrict__ w1h, const unsigned short* __restrict__ w2h,
    const float* __restrict__ b1, float* __restrict__ out)
{
    __shared__ __align__(16) unsigned short sb[32768];  // 64KB: Ah|Al|Bh|Bl (8192 each)
    __shared__ int rows[TM];
    __shared__ int hdr[3];
    const int tid = threadIdx.x;
    const int cc = blockIdx.x;

    if (tid == 0) {
        int ty = blockIdx.y, acc0 = 0, e = -1, t = 0;
        for (int i = 0; i < NE; ++i) {
            int te = (ws[WS_COUNTS + i] + TM - 1) / TM;
            if (ty < acc0 + te) { e = i; t = ty - acc0; break; }
            acc0 += te;
        }
        hdr[0] = e;
        if (e >= 0) {
            hdr[1] = min(TM, ws[WS_COUNTS + e] - t * TM);
            hdr[2] = ws[WS_OFF + e] + t * TM;
        }
    }
    __syncthreads();
    const int e = hdr[0];
    if (e < 0) return;
    const int nr = hdr[1];
    if (tid < TM) rows[tid] = ws[WS_ROWS + hdr[2] + min(tid, nr - 1)];
    __syncthreads();

    const int wave = tid >> 6, lane = tid & 63;
    const int wm = wave >> 1, wn = wave & 1;
    const int lg = lane >> 4, ln = lane & 15;
    const int l7 = ln & 7;

    // staging source pointers (unit = tid + 256*i; 16B per lane)
    const unsigned short* pA[4];
    const unsigned short* pB[4];
#pragma unroll
    for (int i = 0; i < 4; ++i) {
        int u = tid + 256 * i;
        int r = u >> 3, g = u & 7;
        pA[i] = xh + (size_t)rows[r] * F1 + (g ^ (r & 7)) * 8;
        pB[i] = w1h + ((size_t)e * F2 + cc * 128 + r) * F1 + ((g ^ (r & 7)) * 8);
    }

    float bias[4];
#pragma unroll
    for (int nf = 0; nf < 4; ++nf)
        bias[nf] = b1[e * F2 + cc * 128 + wn * 64 + nf * 16 + ln];

    f32x4 acc[4][4];
#pragma unroll
    for (int m = 0; m < 4; ++m)
#pragma unroll
        for (int n = 0; n < 4; ++n) acc[m][n] = (f32x4){0.f, 0.f, 0.f, 0.f};

    const int wb = wave * 512;  // wave chunk base (ushorts)
    for (int kt = 0; kt < F1 / BK; ++kt) {
        const int k0 = kt * BK;
#pragma unroll
        for (int i = 0; i < 4; ++i) {
            gl16(pA[i] + k0,          &sb[wb + i * 2048]);
            gl16(pA[i] + SZ_X + k0,   &sb[8192 + wb + i * 2048]);
            gl16(pB[i] + k0,          &sb[16384 + wb + i * 2048]);
            gl16(pB[i] + SZ_W1 + k0,  &sb[24576 + wb + i * 2048]);
        }
        __syncthreads();
#pragma unroll
        for (int kk = 0; kk < 2; ++kk) {
            const int sz = (kk * 4 + lg) ^ l7;
            s16x8 ah[4], al[4];
#pragma unroll
            for (int m = 0; m < 4; ++m) {
                int off = (wm * 64 + m * 16 + ln) * 64 + sz * 8;
                ah[m] = *(const s16x8*)&sb[off];
                al[m] = *(const s16x8*)&sb[8192 + off];
            }
#pragma unroll
            for (int n = 0; n < 4; ++n) {
                int off = (wn * 64 + n * 16 + ln) * 64 + sz * 8;
                s16x8 bh = *(const s16x8*)&sb[16384 + off];
                s16x8 bl = *(const s16x8*)&sb[24576 + off];
#pragma unroll
                for (int m = 0; m < 4; ++m) {
                    acc[m][n] = __builtin_amdgcn_mfma_f32_16x16x32_bf16(ah[m], bh, acc[m][n], 0, 0, 0);
                    acc[m][n] = __builtin_amdgcn_mfma_f32_16x16x32_bf16(al[m], bh, acc[m][n], 0, 0, 0);
                    acc[m][n] = __builtin_amdgcn_mfma_f32_16x16x32_bf16(ah[m], bl, acc[m][n], 0, 0, 0);
                }
            }
        }
        __syncthreads();
    }

    // ---- phase B: logits partials = relu(h + b1) @ W2t, k2 in 2 halves ----
    f32x4 acc2[2][7];
#pragma unroll
    for (int mf = 0; mf < 2; ++mf)
#pragma unroll
        for (int cf = 0; cf < 7; ++cf) acc2[mf][cf] = (f32x4){0.f, 0.f, 0.f, 0.f};

#pragma unroll
    for (int s = 0; s < 2; ++s) {
        __syncthreads();
        if (wn == s) {
#pragma unroll
            for (int m = 0; m < 4; ++m)
#pragma unroll
                for (int nf = 0; nf < 4; ++nf) {
                    const float bb = bias[nf];
                    const int k2 = nf * 16 + ln;
#pragma unroll
                    for (int reg = 0; reg < 4; ++reg) {
                        int row = wm * 64 + m * 16 + lg * 4 + reg;
                        float v = fmaxf(acc[m][nf][reg] + bb, 0.f);
                        unsigned short hh = bf_hi(v);
                        int off = row * 64 + ((k2 >> 3) ^ (row & 7)) * 8 + (k2 & 7);
                        sb[off] = hh;
                        sb[8192 + off] = bf_hi(v - bf_up(hh));
                    }
                }
        }
        for (int ch = wave; ch < 14; ch += 4) {  // 896 units = 14 chunks of 64
            int u = ch * 64 + lane;
            int c = u >> 3, g = u & 7;
            const unsigned short* src =
                w2h + ((size_t)e * NCP + c) * F2 + cc * 128 + s * 64 + ((g ^ (c & 7)) * 8);
            gl16(src,         &sb[16384 + ch * 512]);
            gl16(src + SZ_W2, &sb[24576 + ch * 512]);
        }
        __syncthreads();
#pragma unroll
        for (int kk = 0; kk < 2; ++kk) {
            const int sz = (kk * 4 + lg) ^ l7;
            s16x8 hh[2], hl[2];
#pragma unroll
            for (int mf = 0; mf < 2; ++mf) {
                int off = (wave * 32 + mf * 16 + ln) * 64 + sz * 8;
                hh[mf] = *(const s16x8*)&sb[off];
                hl[mf] = *(const s16x8*)&sb[8192 + off];
            }
#pragma unroll
            for (int cf = 0; cf < 7; ++cf) {
                int off = (cf * 16 + ln) * 64 + sz * 8;
                s16x8 wh = *(const s16x8*)&sb[16384 + off];
                s16x8 wl = *(const s16x8*)&sb[24576 + off];
#pragma unroll
                for (int mf = 0; mf < 2; ++mf) {
                    acc2[mf][cf] = __builtin_amdgcn_mfma_f32_16x16x32_bf16(hh[mf], wh, acc2[mf][cf], 0, 0, 0);
                    acc2[mf][cf] = __builtin_amdgcn_mfma_f32_16x16x32_bf16(hl[mf], wh, acc2[mf][cf], 0, 0, 0);
                    acc2[mf][cf] = __builtin_amdgcn_mfma_f32_16x16x32_bf16(hh[mf], wl, acc2[mf][cf], 0, 0, 0);
                }
            }
        }
    }

#pragma unroll
    for (int mf = 0; mf < 2; ++mf)
#pragma unroll
        for (int cf = 0; cf < 7; ++cf)
#pragma unroll
            for (int reg = 0; reg < 4; ++reg) {
                int row = wave * 32 + mf * 16 + lg * 4 + reg;
                int c = cf * 16 + ln;
                if (row < nr && c < NC)
                    atomicAdd(out + (size_t)rows[row] * NC + c, acc2[mf][cf][reg]);
            }
}

__global__ void k_sm(const int* __restrict__ dom, const float* __restrict__ b2,
                     float* __restrict__ out)
{
    const int row = blockIdx.x * 4 + (threadIdx.x >> 6);
    const int lane = threadIdx.x & 63;
    const int e = dom[row];
    float* base = out + (size_t)row * NC;
    float v0 = base[lane] + b2[e * NC + lane];
    float v1 = -1e30f;
    if (lane + 64 < NC) v1 = base[lane + 64] + b2[e * NC + lane + 64];
    float m = fmaxf(v0, v1);
#pragma unroll
    for (int s = 1; s < 64; s <<= 1) m = fmaxf(m, __shfl_xor(m, s));
    float p0 = expf(v0 - m);
    float p1 = (lane + 64 < NC) ? expf(v1 - m) : 0.f;
    float sum = p0 + p1;
#pragma unroll
    for (int s = 1; s < 64; s <<= 1) sum += __shfl_xor(sum, s);
    float inv = 1.f / sum;
    base[lane] = p0 * inv;
    if (lane + 64 < NC) base[lane + 64] = p1 * inv;
}

extern "C" void kernel_launch(void* const* d_in, const int* in_sizes, int n_in,
                              void* d_out, int out_size, void* d_ws, size_t ws_size,
                              hipStream_t stream)
{
    const int*   dom = (const int*)d_in[0];
    const float* x   = (const float*)d_in[1];
    const float* W1  = (const float*)d_in[2];
    const float* b1  = (const float*)d_in[3];
    const float* W2  = (const float*)d_in[4];
    const float* b2  = (const float*)d_in[5];
    float*       out = (float*)d_out;
    int*         ws  = (int*)d_ws;

    unsigned short* xh  = (unsigned short*)((char*)d_ws + OFF_XH);
    unsigned short* w1h = (unsigned short*)((char*)d_ws + OFF_W1H);
    unsigned short* w2h = (unsigned short*)((char*)d_ws + OFF_W2H);

    hipMemsetAsync(ws, 0, 64 * sizeof(int), stream);
    hipMemsetAsync(out, 0, (size_t)NB * NC * sizeof(float), stream);
    hipLaunchKernelGGL(k_hist,     dim3(NB / 256), dim3(256), 0, stream, dom, ws);
    hipLaunchKernelGGL(k_scan,     dim3(1), dim3(1), 0, stream, ws);
    hipLaunchKernelGGL(k_scatter,  dim3(NB / 256), dim3(256), 0, stream, dom, ws);
    hipLaunchKernelGGL(k_split_x,  dim3(NB * F1 / 1024), dim3(256), 0, stream, x, xh);
    hipLaunchKernelGGL(k_split_w1t, dim3(F2 / 64, F1 / 64, NE), dim3(256), 0, stream, W1, w1h);
    hipLaunchKernelGGL(k_split_w2t, dim3(F2 / 64, NE), dim3(256), 0, stream, W2, w2h);
    hipLaunchKernelGGL(k_g1,       dim3(NCC, MAXTY), dim3(256), 0, stream,
                       ws, xh, w1h, w2h, b1, out);
    hipLaunchKernelGGL(k_sm,       dim3(NB / 4), dim3(256), 0, stream, dom, b2, out);
}

// Round 4
// 384.843 us; speedup vs baseline: 6.7286x; 1.1076x over previous
//
#include <hip/hip_runtime.h>
#include <math.h>

#define NB 8192
#define NE 8
#define F1 1024
#define F2 2048
#define NC 100
#define NCP 112
#define TM 128
#define BK 32
#define NKT (F1 / BK)    // 32
#define NCC (F2 / 128)   // 16
#define MAXTY 72

#define WS_CUR   17      // 8 cursors
#define WS_TYE   32      // 72
#define WS_TYR   104     // 72
#define WS_TYN   176     // 72
#define WS_ROWS  256     // 8192

#define OFF_XH  ((size_t)65536)
#define SZ_X    ((size_t)NB * F1)
#define OFF_W1H (OFF_XH + 4 * SZ_X)
#define SZ_W1   ((size_t)NE * F2 * F1)
#define OFF_W2H (OFF_W1H + 4 * SZ_W1)
#define SZ_W2   ((size_t)NE * NCP * F2)

typedef float f32x4 __attribute__((ext_vector_type(4)));
typedef short s16x8 __attribute__((ext_vector_type(8)));
typedef unsigned short u16x8 __attribute__((ext_vector_type(8)));
typedef unsigned short u16x4 __attribute__((ext_vector_type(4)));

__device__ __forceinline__ unsigned short bf_hi(float f) {
    unsigned u = __float_as_uint(f);
    return (unsigned short)((u + 0x7FFFu + ((u >> 16) & 1u)) >> 16);  // RNE
}
__device__ __forceinline__ float bf_up(unsigned short h) {
    return __uint_as_float(((unsigned)h) << 16);
}

typedef const __attribute__((address_space(1))) unsigned cgu;
typedef __attribute__((address_space(3))) unsigned ldu;
__device__ __forceinline__ void gl16(const void* g, void* l) {
    __builtin_amdgcn_global_load_lds((cgu*)g, (ldu*)l, 16, 0, 0);
}

// -------- planning: histogram (ballot), offsets, cursors, ty table --------
__global__ __launch_bounds__(512) void k_plan(const int* __restrict__ dom, int* ws) {
    __shared__ int wh[8][8];
    const int tid = threadIdx.x, wave = tid >> 6, lane = tid & 63;
    int cnt[NE];
#pragma unroll
    for (int e = 0; e < NE; ++e) cnt[e] = 0;
    for (int i = tid; i < NB / 4; i += 512) {
        int4 d = ((const int4*)dom)[i];
        int v[4] = {d.x, d.y, d.z, d.w};
#pragma unroll
        for (int t = 0; t < 4; ++t)
#pragma unroll
            for (int e = 0; e < NE; ++e)
                cnt[e] += (int)__popcll(__ballot(v[t] == e));
    }
    if (lane == 0)
#pragma unroll
        for (int e = 0; e < NE; ++e) wh[wave][e] = cnt[e];
    __syncthreads();
    if (tid == 0) {
        int c[NE], off = 0, ty = 0;
        for (int e = 0; e < NE; ++e) {
            c[e] = 0;
            for (int w = 0; w < 8; ++w) c[e] += wh[w][e];
        }
        for (int e = 0; e < NE; ++e) {
            ws[WS_CUR + e] = off;
            int nt = (c[e] + TM - 1) / TM;
            for (int t = 0; t < nt; ++t) {
                ws[WS_TYE + ty] = e;
                ws[WS_TYR + ty] = off + t * TM;
                ws[WS_TYN + ty] = min(TM, c[e] - t * TM);
                ++ty;
            }
            off += c[e];
        }
        for (; ty < MAXTY; ++ty) ws[WS_TYN + ty] = 0;
    }
}

// -------- scatter with per-block reservation (256 global atomics total) ----
__global__ __launch_bounds__(256) void k_scatter(const int* __restrict__ dom, int* ws) {
    __shared__ int lh[NE], base[NE];
    const int tid = threadIdx.x;
    if (tid < NE) lh[tid] = 0;
    __syncthreads();
    const int b = blockIdx.x * 256 + tid;
    const int e = dom[b];
    const int r = atomicAdd(&lh[e], 1);
    __syncthreads();
    if (tid < NE) base[tid] = atomicAdd(&ws[WS_CUR + tid], lh[tid]);
    __syncthreads();
    ws[WS_ROWS + base[e] + r] = b;
}

// -------- x f32 -> bf16 hi/lo planes --------
__global__ void k_split_x(const float* __restrict__ x, unsigned short* __restrict__ xh) {
    unsigned short* xl = xh + SZ_X;
#pragma unroll
    for (int q = 0; q < 4; ++q) {
        size_t i = (size_t)blockIdx.x * 1024 + q * 256 + threadIdx.x;
        float4 v = *(const float4*)(x + i * 4);
        u16x4 h, l;
        float f[4] = {v.x, v.y, v.z, v.w};
#pragma unroll
        for (int t = 0; t < 4; ++t) {
            unsigned short hh = bf_hi(f[t]);
            h[t] = hh;
            l[t] = bf_hi(f[t] - bf_up(hh));
        }
        *(u16x4*)(xh + i * 4) = h;
        *(u16x4*)(xl + i * 4) = l;
    }
}

// -------- W1[e][k][n] -> W1t[e][n][k] bf16 hi/lo (odd-stride LDS transpose) --------
__global__ void k_split_w1t(const float* __restrict__ W1, unsigned short* __restrict__ w1h) {
    unsigned short* w1l = w1h + SZ_W1;
    __shared__ float t[64][65];
    const int e = blockIdx.z, k0 = blockIdx.y * 64, n0 = blockIdx.x * 64;
    const float* src = W1 + ((size_t)e * F1 + k0) * F2 + n0;
#pragma unroll
    for (int i = 0; i < 4; ++i) {
        int u = threadIdx.x + 256 * i;
        int k = u >> 4, n4 = (u & 15) * 4;
        float4 v = *(const float4*)(src + (size_t)k * F2 + n4);
        t[k][n4] = v.x; t[k][n4 + 1] = v.y; t[k][n4 + 2] = v.z; t[k][n4 + 3] = v.w;
    }
    __syncthreads();
#pragma unroll
    for (int i = 0; i < 2; ++i) {
        int u = threadIdx.x + 256 * i;
        int n = u >> 3, kg = u & 7;
        u16x8 hv, lv;
#pragma unroll
        for (int j = 0; j < 8; ++j) {
            float v = t[kg * 8 + j][n];
            unsigned short hh = bf_hi(v);
            hv[j] = hh;
            lv[j] = bf_hi(v - bf_up(hh));
        }
        size_t dst = ((size_t)e * F2 + n0 + n) * F1 + k0 + kg * 8;
        *(u16x8*)(w1h + dst) = hv;
        *(u16x8*)(w1l + dst) = lv;
    }
}

// -------- W2[e][k2][c] -> W2t[e][c(pad112)][k2] bf16 hi/lo --------
__global__ void k_split_w2t(const float* __restrict__ W2, unsigned short* __restrict__ w2h) {
    unsigned short* w2l = w2h + SZ_W2;
    __shared__ float t[64][NC + 1];
    const int e = blockIdx.y, k0 = blockIdx.x * 64;
    const float* src = W2 + ((size_t)e * F2 + k0) * NC;
    for (int u = threadIdx.x; u < 64 * NC; u += 256) {
        int k = u / NC, c = u - k * NC;
        t[k][c] = src[u];
    }
    __syncthreads();
#pragma unroll
    for (int i = 0; i < 4; ++i) {
        int u = threadIdx.x + 256 * i;
        if (u < NCP * 8) {
            int c = u >> 3, kg = u & 7;
            u16x8 hv, lv;
#pragma unroll
            for (int j = 0; j < 8; ++j) {
                float v = (c < NC) ? t[kg * 8 + j][c] : 0.f;
                unsigned short hh = bf_hi(v);
                hv[j] = hh;
                lv[j] = bf_hi(v - bf_up(hh));
            }
            size_t dst = ((size_t)e * NCP + c) * F2 + k0 + kg * 8;
            *(u16x8*)(w2h + dst) = hv;
            *(u16x8*)(w2l + dst) = lv;
        }
    }
}

// -------- fused grouped GEMM, double-buffered + counted vmcnt --------
// Phase-A LDS plane (BK=32): ushort off(r, g, j) = r*32 + (g ^ (r&3))*8 + j
// Buffers: buf d at d*16384; planes Ah+0, Al+4096, Bh+8192, Bl+12288 (ushorts)
__global__ __launch_bounds__(256, 2) void k_g1(
    const int* __restrict__ ws, const unsigned short* __restrict__ xh,
    const unsigned short* __restrict__ w1h, const unsigned short* __restrict__ w2h,
    const float* __restrict__ b1, float* __restrict__ out)
{
    __shared__ __align__(16) unsigned short sb[32768];  // 64 KB
    __shared__ int rows[TM];
    const int tid = threadIdx.x;
    const int cc = blockIdx.x;
    const int ty = blockIdx.y;

    const int nr = ws[WS_TYN + ty];
    if (nr <= 0) return;
    const int e = ws[WS_TYE + ty];
    const int rbase = ws[WS_TYR + ty];
    if (tid < TM) rows[tid] = ws[WS_ROWS + rbase + min(tid, nr - 1)];
    __syncthreads();

    const int wave = tid >> 6, lane = tid & 63;
    const int wm = wave >> 1, wn = wave & 1;
    const int lg = lane >> 4, ln = lane & 15;
    const int l7 = ln & 7;

    // staging sources: plane unit u = wave*64 + lane + 256*i, r=u>>2, s=u&3
    const unsigned short* pA[2];
    const unsigned short* pB[2];
#pragma unroll
    for (int i = 0; i < 2; ++i) {
        int u = tid + 256 * i;
        int r = u >> 2, s = u & 3, g = s ^ (r & 3);
        pA[i] = xh + (size_t)rows[r] * F1 + g * 8;
        pB[i] = w1h + ((size_t)e * F2 + cc * 128 + r) * F1 + g * 8;
    }
    const int ldst0 = tid * 8;          // ushort offset of this thread's 16B slot
    const int ldst1 = ldst0 + 2048;

    float bias[4];
#pragma unroll
    for (int nf = 0; nf < 4; ++nf)
        bias[nf] = b1[e * F2 + cc * 128 + wn * 64 + nf * 16 + ln];

    f32x4 acc[4][4];
#pragma unroll
    for (int m = 0; m < 4; ++m)
#pragma unroll
        for (int n = 0; n < 4; ++n) acc[m][n] = (f32x4){0.f, 0.f, 0.f, 0.f};

#define STAGE(kt, db)                                                          \
    {                                                                          \
        const int ko = (kt) * BK;                                              \
        const int b0 = (db) * 16384;                                           \
        gl16(pA[0] + ko,         &sb[b0 + ldst0]);                             \
        gl16(pA[1] + ko,         &sb[b0 + ldst1]);                             \
        gl16(pA[0] + SZ_X + ko,  &sb[b0 + 4096 + ldst0]);                      \
        gl16(pA[1] + SZ_X + ko,  &sb[b0 + 4096 + ldst1]);                      \
        gl16(pB[0] + ko,         &sb[b0 + 8192 + ldst0]);                      \
        gl16(pB[1] + ko,         &sb[b0 + 8192 + ldst1]);                      \
        gl16(pB[0] + SZ_W1 + ko, &sb[b0 + 12288 + ldst0]);                     \
        gl16(pB[1] + SZ_W1 + ko, &sb[b0 + 12288 + ldst1]);                     \
    }

    STAGE(0, 0);
    for (int kt = 0; kt < NKT; ++kt) {
        const int cur = kt & 1;
        if (kt + 1 < NKT) {
            STAGE(kt + 1, cur ^ 1);
            asm volatile("s_waitcnt vmcnt(8)" ::: "memory");
        } else {
            asm volatile("s_waitcnt vmcnt(0)" ::: "memory");
        }
        __builtin_amdgcn_s_barrier();
        __builtin_amdgcn_sched_barrier(0);
        const int b0 = cur * 16384;
        s16x8 ah[4], al[4];
#pragma unroll
        for (int m = 0; m < 4; ++m) {
            int r = wm * 64 + m * 16 + ln;
            int off = b0 + r * 32 + (lg ^ (r & 3)) * 8;
            ah[m] = *(const s16x8*)&sb[off];
            al[m] = *(const s16x8*)&sb[4096 + off];
        }
#pragma unroll
        for (int n = 0; n < 4; ++n) {
            int r = wn * 64 + n * 16 + ln;
            int off = b0 + 8192 + r * 32 + (lg ^ (r & 3)) * 8;
            s16x8 bh = *(const s16x8*)&sb[off];
            s16x8 bl = *(const s16x8*)&sb[4096 + off];
#pragma unroll
            for (int m = 0; m < 4; ++m) {
                acc[m][n] = __builtin_amdgcn_mfma_f32_16x16x32_bf16(ah[m], bh, acc[m][n], 0, 0, 0);
                acc[m][n] = __builtin_amdgcn_mfma_f32_16x16x32_bf16(al[m], bh, acc[m][n], 0, 0, 0);
                acc[m][n] = __builtin_amdgcn_mfma_f32_16x16x32_bf16(ah[m], bl, acc[m][n], 0, 0, 0);
            }
        }
        __builtin_amdgcn_sched_barrier(0);
        __builtin_amdgcn_s_barrier();
    }
#undef STAGE

    // ---- phase B: logits partials = relu(h + b1) @ W2t, k2 in 2 halves ----
    // H planes (128 rows x 64 k2): off = row*64 + ((k2>>3) ^ (row&7))*8 + (k2&7)
    f32x4 acc2[2][7];
#pragma unroll
    for (int mf = 0; mf < 2; ++mf)
#pragma unroll
        for (int cf = 0; cf < 7; ++cf) acc2[mf][cf] = (f32x4){0.f, 0.f, 0.f, 0.f};

#pragma unroll
    for (int s = 0; s < 2; ++s) {
        __syncthreads();
        if (wn == s) {
#pragma unroll
            for (int m = 0; m < 4; ++m)
#pragma unroll
                for (int nf = 0; nf < 4; ++nf) {
                    const float bb = bias[nf];
                    const int k2 = nf * 16 + ln;
#pragma unroll
                    for (int reg = 0; reg < 4; ++reg) {
                        int row = wm * 64 + m * 16 + lg * 4 + reg;
                        float v = fmaxf(acc[m][nf][reg] + bb, 0.f);
                        unsigned short hh = bf_hi(v);
                        int off = row * 64 + ((k2 >> 3) ^ (row & 7)) * 8 + (k2 & 7);
                        sb[off] = hh;
                        sb[8192 + off] = bf_hi(v - bf_up(hh));
                    }
                }
        }
        for (int ch = wave; ch < 14; ch += 4) {  // 896 units: W2t c-rows x slots
            int u = ch * 64 + lane;
            int c = u >> 3, g = u & 7;
            const unsigned short* src =
                w2h + ((size_t)e * NCP + c) * F2 + cc * 128 + s * 64 + ((g ^ (c & 7)) * 8);
            gl16(src,         &sb[16384 + ch * 512]);
            gl16(src + SZ_W2, &sb[24576 + ch * 512]);
        }
        __syncthreads();
#pragma unroll
        for (int kk = 0; kk < 2; ++kk) {
            const int sz = (kk * 4 + lg) ^ l7;
            s16x8 hh[2], hl[2];
#pragma unroll
            for (int mf = 0; mf < 2; ++mf) {
                int off = (wave * 32 + mf * 16 + ln) * 64 + sz * 8;
                hh[mf] = *(const s16x8*)&sb[off];
                hl[mf] = *(const s16x8*)&sb[8192 + off];
            }
#pragma unroll
            for (int cf = 0; cf < 7; ++cf) {
                int off = (cf * 16 + ln) * 64 + sz * 8;
                s16x8 wh = *(const s16x8*)&sb[16384 + off];
                s16x8 wl = *(const s16x8*)&sb[24576 + off];
#pragma unroll
                for (int mf = 0; mf < 2; ++mf) {
                    acc2[mf][cf] = __builtin_amdgcn_mfma_f32_16x16x32_bf16(hh[mf], wh, acc2[mf][cf], 0, 0, 0);
                    acc2[mf][cf] = __builtin_amdgcn_mfma_f32_16x16x32_bf16(hl[mf], wh, acc2[mf][cf], 0, 0, 0);
                    acc2[mf][cf] = __builtin_amdgcn_mfma_f32_16x16x32_bf16(hh[mf], wl, acc2[mf][cf], 0, 0, 0);
                }
            }
        }
    }

#pragma unroll
    for (int mf = 0; mf < 2; ++mf)
#pragma unroll
        for (int cf = 0; cf < 7; ++cf)
#pragma unroll
            for (int reg = 0; reg < 4; ++reg) {
                int row = wave * 32 + mf * 16 + lg * 4 + reg;
                int c = cf * 16 + ln;
                if (row < nr && c < NC)
                    atomicAdd(out + (size_t)rows[row] * NC + c, acc2[mf][cf][reg]);
            }
}

__global__ void k_sm(const int* __restrict__ dom, const float* __restrict__ b2,
                     float* __restrict__ out)
{
    const int row = blockIdx.x * 4 + (threadIdx.x >> 6);
    const int lane = threadIdx.x & 63;
    const int e = dom[row];
    float* base = out + (size_t)row * NC;
    float v0 = base[lane] + b2[e * NC + lane];
    float v1 = -1e30f;
    if (lane + 64 < NC) v1 = base[lane + 64] + b2[e * NC + lane + 64];
    float m = fmaxf(v0, v1);
#pragma unroll
    for (int s = 1; s < 64; s <<= 1) m = fmaxf(m, __shfl_xor(m, s));
    float p0 = expf(v0 - m);
    float p1 = (lane + 64 < NC) ? expf(v1 - m) : 0.f;
    float sum = p0 + p1;
#pragma unroll
    for (int s = 1; s < 64; s <<= 1) sum += __shfl_xor(sum, s);
    float inv = 1.f / sum;
    base[lane] = p0 * inv;
    if (lane + 64 < NC) base[lane + 64] = p1 * inv;
}

extern "C" void kernel_launch(void* const* d_in, const int* in_sizes, int n_in,
                              void* d_out, int out_size, void* d_ws, size_t ws_size,
                              hipStream_t stream)
{
    const int*   dom = (const int*)d_in[0];
    const float* x   = (const float*)d_in[1];
    const float* W1  = (const float*)d_in[2];
    const float* b1  = (const float*)d_in[3];
    const float* W2  = (const float*)d_in[4];
    const float* b2  = (const float*)d_in[5];
    float*       out = (float*)d_out;
    int*         ws  = (int*)d_ws;

    unsigned short* xh  = (unsigned short*)((char*)d_ws + OFF_XH);
    unsigned short* w1h = (unsigned short*)((char*)d_ws + OFF_W1H);
    unsigned short* w2h = (unsigned short*)((char*)d_ws + OFF_W2H);

    hipMemsetAsync(out, 0, (size_t)NB * NC * sizeof(float), stream);
    hipLaunchKernelGGL(k_plan,      dim3(1), dim3(512), 0, stream, dom, ws);
    hipLaunchKernelGGL(k_scatter,   dim3(NB / 256), dim3(256), 0, stream, dom, ws);
    hipLaunchKernelGGL(k_split_x,   dim3(NB * F1 / 4096), dim3(256), 0, stream, x, xh);
    hipLaunchKernelGGL(k_split_w1t, dim3(F2 / 64, F1 / 64, NE), dim3(256), 0, stream, W1, w1h);
    hipLaunchKernelGGL(k_split_w2t, dim3(F2 / 64, NE), dim3(256), 0, stream, W2, w2h);
    hipLaunchKernelGGL(k_g1,        dim3(NCC, MAXTY), dim3(256), 0, stream,
                       ws, xh, w1h, w2h, b1, out);
    hipLaunchKernelGGL(k_sm,        dim3(NB / 4), dim3(256), 0, stream, dom, b2, out);
}